// Round 1
// baseline (924.402 us; speedup 1.0000x reference)
//
#include <hip/hip_runtime.h>

// Problem dims
// B=512, N=64, H=256, LAT=128, HEADS=4, HC=64, NF=64, L=3, R=8, SCAL=2.0, NB=4
// Din = 384

// ws layout (float offsets)
#define ZA_OFF   0UL          // zA[512][8]
#define NW_OFF   4096UL       // nodeWe[64][256] row-major (effective)
#define AW_OFF   20480UL      // adjWe[512]
#define BW_OFF   20992UL      // bondWe[4][512]
#define X_OFF    24576UL      // x[512][64][256]
#define H_OFF    (X_OFF + 512UL*64*256)   // h[512][64][256]

// ---------------------------------------------------------------- setup ----
__global__ __launch_bounds__(256) void k_setup(
    const float* __restrict__ z, const float* __restrict__ z2nA,
    const float* __restrict__ nodeW, const float* __restrict__ nodeA, const float* __restrict__ nodeB,
    const float* __restrict__ adjW, const float* __restrict__ adjA, const float* __restrict__ adjB,
    const float* __restrict__ bondW, const float* __restrict__ bondA, const float* __restrict__ bondB,
    float* __restrict__ ws)
{
    int gid = blockIdx.x * 256 + threadIdx.x;
    if (gid < 4096) {                       // zA[b][r] = z[b]·A[r]
        int b = gid >> 3, r = gid & 7;
        const float* zp = z + (size_t)b * 128;
        const float* ap = z2nA + (size_t)r * 128;
        float s = 0.f;
        #pragma unroll 8
        for (int k = 0; k < 128; ++k) s += zp[k] * ap[k];
        ws[ZA_OFF + gid] = s;
    } else if (gid < 20480) {               // nodeWe[f][c]
        int i = gid - 4096;
        int f = i >> 8, c = i & 255;
        float s = 0.f;
        #pragma unroll
        for (int r = 0; r < 8; ++r) s += nodeB[f*8+r] * nodeA[r*256+c];
        ws[NW_OFF + i] = nodeW[i] + 2.0f * s;
    } else if (gid < 20992) {               // adjWe[c2]
        int c2 = gid - 20480;
        float s = 0.f;
        #pragma unroll
        for (int r = 0; r < 8; ++r) s += adjB[r] * adjA[r*512+c2];
        ws[AW_OFF + c2] = adjW[c2] + 2.0f * s;
    } else if (gid < 23040) {               // bondWe[q][c2]
        int i = gid - 20992;
        int q = i >> 9, c2 = i & 511;
        float s = 0.f;
        #pragma unroll
        for (int r = 0; r < 8; ++r) s += bondB[q*8+r] * bondA[r*512+c2];
        ws[BW_OFF + i] = bondW[i] + 2.0f * s;
    }
}

// ------------------------------------------------------------- z_to_nodes --
// x[b][o] = relu( z[b]·W[o] + 2*zA[b]·B[o] + bias[o] ),  o = n*256+c
__global__ __launch_bounds__(256) void k_z2n(
    const float* __restrict__ z, const float* __restrict__ w,
    const float* __restrict__ bias, const float* __restrict__ lB,
    float* __restrict__ ws)
{
    __shared__ float zt[64][68];
    __shared__ float wt[64][68];
    __shared__ float zAl[64][8];
    __shared__ float bl[64][8];
    int t = threadIdx.x;
    int bm = blockIdx.x >> 8, bn = blockIdx.x & 255;
    int mb = bm * 64, ob = bn * 64;
    int tr = t >> 4, tc = t & 15;
    if (t < 128) {
        ((float4*)zAl)[t] = ((const float4*)(ws + ZA_OFF + (size_t)mb*8))[t];
    } else {
        ((float4*)bl)[t-128] = ((const float4*)(lB + (size_t)ob*8))[t-128];
    }
    float acc[4][4] = {};
    for (int kc = 0; kc < 2; ++kc) {
        int k0 = kc * 64;
        __syncthreads();
        for (int idx = t; idx < 1024; idx += 256) {
            int row = idx >> 4, k4 = (idx & 15) * 4;
            *(float4*)&zt[row][k4] = *(const float4*)&z[(size_t)(mb+row)*128 + k0 + k4];
            *(float4*)&wt[row][k4] = *(const float4*)&w[(size_t)(ob+row)*128 + k0 + k4];
        }
        __syncthreads();
        #pragma unroll
        for (int k = 0; k < 64; k += 4) {
            float4 av[4], bv[4];
            #pragma unroll
            for (int i = 0; i < 4; ++i) av[i] = *(const float4*)&zt[tr+16*i][k];
            #pragma unroll
            for (int j = 0; j < 4; ++j) bv[j] = *(const float4*)&wt[tc+16*j][k];
            #pragma unroll
            for (int i = 0; i < 4; ++i)
                #pragma unroll
                for (int j = 0; j < 4; ++j)
                    acc[i][j] += av[i].x*bv[j].x + av[i].y*bv[j].y + av[i].z*bv[j].z + av[i].w*bv[j].w;
        }
    }
    #pragma unroll
    for (int i = 0; i < 4; ++i) {
        int rl = tr + 16*i; int b = mb + rl;
        #pragma unroll
        for (int j = 0; j < 4; ++j) {
            int cl = tc + 16*j; int o = ob + cl;
            float lor = 0.f;
            #pragma unroll
            for (int r = 0; r < 8; ++r) lor += zAl[rl][r] * bl[cl][r];
            float v = acc[i][j] + 2.0f*lor + bias[o];
            ws[X_OFF + (size_t)b*16384 + o] = v > 0.f ? v : 0.f;
        }
    }
}

// ---------------------------------------------------------------- GAT h ----
// h[b][n][o2] = xc[b][n]·gatW[l][o2],  xc = concat(x[b][n], z[b])
__global__ __launch_bounds__(256) void k_gat_h(
    const float* __restrict__ z, const float* __restrict__ gatW, int l,
    float* __restrict__ ws)
{
    __shared__ float at[64][68];
    __shared__ float bt[64][68];
    int t = threadIdx.x;
    int b = blockIdx.x >> 2, bn = blockIdx.x & 3;
    int ob = bn * 64;
    int tr = t >> 4, tc = t & 15;
    const float* x = ws + X_OFF + (size_t)b * 16384;
    const float* wl = gatW + (size_t)l * 98304;
    float acc[4][4] = {};
    for (int kc = 0; kc < 6; ++kc) {
        int k0 = kc * 64;
        __syncthreads();
        for (int idx = t; idx < 1024; idx += 256) {
            int row = idx >> 4, k4 = (idx & 15) * 4;
            float4 av;
            if (k0 < 256) av = *(const float4*)&x[(size_t)row*256 + k0 + k4];
            else          av = *(const float4*)&z[(size_t)b*128 + (k0-256) + k4];
            *(float4*)&at[row][k4] = av;
            *(float4*)&bt[row][k4] = *(const float4*)&wl[(size_t)(ob+row)*384 + k0 + k4];
        }
        __syncthreads();
        #pragma unroll
        for (int k = 0; k < 64; k += 4) {
            float4 av[4], bv[4];
            #pragma unroll
            for (int i = 0; i < 4; ++i) av[i] = *(const float4*)&at[tr+16*i][k];
            #pragma unroll
            for (int j = 0; j < 4; ++j) bv[j] = *(const float4*)&bt[tc+16*j][k];
            #pragma unroll
            for (int i = 0; i < 4; ++i)
                #pragma unroll
                for (int j = 0; j < 4; ++j)
                    acc[i][j] += av[i].x*bv[j].x + av[i].y*bv[j].y + av[i].z*bv[j].z + av[i].w*bv[j].w;
        }
    }
    #pragma unroll
    for (int i = 0; i < 4; ++i) {
        int n = tr + 16*i;
        #pragma unroll
        for (int j = 0; j < 4; ++j) {
            int o2 = ob + tc + 16*j;
            ws[H_OFF + (size_t)b*16384 + (size_t)n*256 + o2] = acc[i][j];
        }
    }
}

// ------------------------------------------------------------- attention ---
// one block per (b, head): softmax over sources j, then out = alpha @ h
__global__ __launch_bounds__(256) void k_attn(
    const float* __restrict__ asrc_all, const float* __restrict__ adst_all,
    const float* __restrict__ gbias, int l, float* __restrict__ ws)
{
    __shared__ float hl[64][68];
    __shared__ float alT[64][68];   // alT[j][i]
    __shared__ float esl[64], edl[64];
    int t = threadIdx.x;
    int b = blockIdx.x >> 2, hd = blockIdx.x & 3;
    const float* hsrc = ws + H_OFF + (size_t)b*16384 + hd*64;
    for (int idx = t; idx < 1024; idx += 256) {
        int row = idx >> 4, c4 = (idx & 15) * 4;
        *(float4*)&hl[row][c4] = *(const float4*)&hsrc[(size_t)row*256 + c4];
    }
    __syncthreads();
    if (t < 128) {
        int n = t & 63;
        const float* av = (t < 64 ? asrc_all : adst_all) + l*256 + hd*64;
        float s = 0.f;
        #pragma unroll 8
        for (int c = 0; c < 64; ++c) s += hl[n][c] * av[c];
        if (t < 64) esl[n] = s; else edl[n] = s;
    }
    __syncthreads();
    if (t < 64) {
        int i = t;
        float di = edl[i];
        float m = -1e30f;
        for (int j = 0; j < 64; ++j) {
            float e = di + esl[j];
            e = e > 0.f ? e : 0.2f * e;
            m = fmaxf(m, e);
        }
        float ssum = 0.f;
        for (int j = 0; j < 64; ++j) {
            float e = di + esl[j];
            e = e > 0.f ? e : 0.2f * e;
            float p = __expf(e - m);
            ssum += p;
            alT[j][i] = p;
        }
        float inv = 1.0f / ssum;
        for (int j = 0; j < 64; ++j) alT[j][i] *= inv;
    }
    __syncthreads();
    int tr = t >> 4, tc = t & 15;
    float acc[4][4] = {};
    for (int j = 0; j < 64; ++j) {
        float4 a4 = *(const float4*)&alT[j][tr*4];
        float4 h4 = *(const float4*)&hl[j][tc*4];
        acc[0][0] += a4.x*h4.x; acc[0][1] += a4.x*h4.y; acc[0][2] += a4.x*h4.z; acc[0][3] += a4.x*h4.w;
        acc[1][0] += a4.y*h4.x; acc[1][1] += a4.y*h4.y; acc[1][2] += a4.y*h4.z; acc[1][3] += a4.y*h4.w;
        acc[2][0] += a4.z*h4.x; acc[2][1] += a4.z*h4.y; acc[2][2] += a4.z*h4.z; acc[2][3] += a4.z*h4.w;
        acc[3][0] += a4.w*h4.x; acc[3][1] += a4.w*h4.y; acc[3][2] += a4.w*h4.z; acc[3][3] += a4.w*h4.w;
    }
    const float* bp = gbias + l*256 + hd*64;
    float* xout = ws + X_OFF + (size_t)b*16384 + hd*64;
    #pragma unroll
    for (int q = 0; q < 4; ++q) {
        int i = tr*4 + q;
        float4 v;
        v.x = acc[q][0] + bp[tc*4+0];
        v.y = acc[q][1] + bp[tc*4+1];
        v.z = acc[q][2] + bp[tc*4+2];
        v.w = acc[q][3] + bp[tc*4+3];
        v.x = v.x > 0.f ? v.x : 0.f;
        v.y = v.y > 0.f ? v.y : 0.f;
        v.z = v.z > 0.f ? v.z : 0.f;
        v.w = v.w > 0.f ? v.w : 0.f;
        *(float4*)&xout[(size_t)i*256 + tc*4] = v;
    }
}

// ------------------------------------------------------------- predictors --
__global__ __launch_bounds__(256) void k_pred(
    const float* __restrict__ nodeb, const float* __restrict__ adjb,
    const float* __restrict__ bondb, const float* __restrict__ ws,
    float* __restrict__ out)
{
    __shared__ float xl[64][68];
    __shared__ float wn[64][68];
    __shared__ float s1l[64], s2l[64];
    __shared__ float t1l[64][4], t2l[64][4];
    int t = threadIdx.x;
    int b = blockIdx.x;
    int tr = t >> 4, tc = t & 15;
    int role = t >> 6, n2 = t & 63;
    const float* x      = ws + X_OFF + (size_t)b*16384;
    const float* nodeWe = ws + NW_OFF;
    const float* adjWe  = ws + AW_OFF;
    const float* bondWe = ws + BW_OFF;
    float acc[4][4] = {};
    float p0 = 0.f, p1 = 0.f, p2 = 0.f, p3 = 0.f;
    for (int kc = 0; kc < 4; ++kc) {
        int k0 = kc * 64;
        __syncthreads();
        for (int idx = t; idx < 1024; idx += 256) {
            int row = idx >> 4, k4 = (idx & 15) * 4;
            *(float4*)&xl[row][k4] = *(const float4*)&x[(size_t)row*256 + k0 + k4];
            *(float4*)&wn[row][k4] = *(const float4*)&nodeWe[(size_t)row*256 + k0 + k4];
        }
        __syncthreads();
        #pragma unroll
        for (int k = 0; k < 64; k += 4) {
            float4 av[4], bv[4];
            #pragma unroll
            for (int i = 0; i < 4; ++i) av[i] = *(const float4*)&xl[tr+16*i][k];
            #pragma unroll
            for (int j = 0; j < 4; ++j) bv[j] = *(const float4*)&wn[tc+16*j][k];
            #pragma unroll
            for (int i = 0; i < 4; ++i)
                #pragma unroll
                for (int j = 0; j < 4; ++j)
                    acc[i][j] += av[i].x*bv[j].x + av[i].y*bv[j].y + av[i].z*bv[j].z + av[i].w*bv[j].w;
        }
        if (role == 0) {
            for (int c = 0; c < 64; ++c) p0 += xl[n2][c] * adjWe[k0+c];
        } else if (role == 1) {
            for (int c = 0; c < 64; ++c) p0 += xl[n2][c] * adjWe[256+k0+c];
        } else if (role == 2) {
            for (int c = 0; c < 64; ++c) {
                float xv = xl[n2][c];
                p0 += xv*bondWe[k0+c];      p1 += xv*bondWe[512+k0+c];
                p2 += xv*bondWe[1024+k0+c]; p3 += xv*bondWe[1536+k0+c];
            }
        } else {
            for (int c = 0; c < 64; ++c) {
                float xv = xl[n2][c];
                p0 += xv*bondWe[256+k0+c];  p1 += xv*bondWe[768+k0+c];
                p2 += xv*bondWe[1280+k0+c]; p3 += xv*bondWe[1792+k0+c];
            }
        }
    }
    __syncthreads();
    if (role == 0)      s1l[n2] = p0;
    else if (role == 1) s2l[n2] = p0;
    else if (role == 2) { t1l[n2][0]=p0; t1l[n2][1]=p1; t1l[n2][2]=p2; t1l[n2][3]=p3; }
    else                { t2l[n2][0]=p0; t2l[n2][1]=p1; t2l[n2][2]=p2; t2l[n2][3]=p3; }
    __syncthreads();
    // node recon: out[b][n][f] = acc + node_b[f]
    #pragma unroll
    for (int i = 0; i < 4; ++i) {
        int n = tr + 16*i;
        #pragma unroll
        for (int j = 0; j < 4; ++j) {
            int f = tc + 16*j;
            out[(size_t)b*4096 + (size_t)n*64 + f] = acc[i][j] + nodeb[f];
        }
    }
    // adj logits
    float ab = adjb[0];
    {
        int i = t >> 2, jg = (t & 3) * 16;
        #pragma unroll
        for (int u4 = 0; u4 < 4; ++u4) {
            float4 v;
            float* vp = (float*)&v;
            #pragma unroll
            for (int uu = 0; uu < 4; ++uu) {
                int j = jg + u4*4 + uu;
                float val;
                if (i == j)      val = 0.f;
                else if (i < j)  val = s1l[i] + s2l[j] + ab;
                else             val = s1l[j] + s2l[i] + ab;
                vp[uu] = val;
            }
            *(float4*)&out[2097152UL + (size_t)b*4096 + (size_t)i*64 + jg + u4*4] = v;
        }
    }
    // bond logits
    float4 bb4 = *(const float4*)bondb;
    {
        int i = t >> 2, jg = (t & 3) * 16;
        #pragma unroll
        for (int u = 0; u < 16; ++u) {
            int j = jg + u;
            float4 v;
            if (i == j) { v.x = v.y = v.z = v.w = 0.f; }
            else {
                int a = i < j ? i : j, c = i < j ? j : i;
                v.x = t1l[a][0] + t2l[c][0] + bb4.x;
                v.y = t1l[a][1] + t2l[c][1] + bb4.y;
                v.z = t1l[a][2] + t2l[c][2] + bb4.z;
                v.w = t1l[a][3] + t2l[c][3] + bb4.w;
            }
            *(float4*)&out[4194304UL + (size_t)b*16384 + (size_t)(i*64+j)*4] = v;
        }
    }
}

// ------------------------------------------------------------------ host ---
extern "C" void kernel_launch(void* const* d_in, const int* in_sizes, int n_in,
                              void* d_out, int out_size, void* d_ws, size_t ws_size,
                              hipStream_t stream)
{
    const float* z     = (const float*)d_in[0];
    const float* z2nw  = (const float*)d_in[1];
    const float* z2nb  = (const float*)d_in[2];
    const float* z2nA  = (const float*)d_in[3];
    const float* z2nB  = (const float*)d_in[4];
    const float* gatW  = (const float*)d_in[5];
    const float* asrc  = (const float*)d_in[6];
    const float* adst  = (const float*)d_in[7];
    const float* gbias = (const float*)d_in[8];
    const float* nodew = (const float*)d_in[9];
    const float* nodeb = (const float*)d_in[10];
    const float* nodeA = (const float*)d_in[11];
    const float* nodeB = (const float*)d_in[12];
    const float* adjw  = (const float*)d_in[13];
    const float* adjb  = (const float*)d_in[14];
    const float* adjA  = (const float*)d_in[15];
    const float* adjB  = (const float*)d_in[16];
    const float* bondw = (const float*)d_in[17];
    const float* bondb = (const float*)d_in[18];
    const float* bondA = (const float*)d_in[19];
    const float* bondB = (const float*)d_in[20];
    float* ws  = (float*)d_ws;
    float* out = (float*)d_out;

    k_setup<<<96, 256, 0, stream>>>(z, z2nA, nodew, nodeA, nodeB,
                                    adjw, adjA, adjB, bondw, bondA, bondB, ws);
    k_z2n<<<2048, 256, 0, stream>>>(z, z2nw, z2nb, z2nB, ws);
    for (int l = 0; l < 3; ++l) {
        k_gat_h<<<2048, 256, 0, stream>>>(z, gatW, l, ws);
        k_attn<<<2048, 256, 0, stream>>>(asrc, adst, gbias, l, ws);
    }
    k_pred<<<512, 256, 0, stream>>>(nodeb, adjb, bondb, ws, out);
}

// Round 2
// 225.055 us; speedup vs baseline: 4.1074x; 4.1074x over previous
//
#include <hip/hip_runtime.h>

// B=512, N=64, H=256, LAT=128, HEADS=4, HC=64, NF=64, L=3, R=8, SCAL=2.0, NB=4, Din=384

typedef float float4v __attribute__((ext_vector_type(4)));
typedef short short8v __attribute__((ext_vector_type(8)));

struct alignas(8) us4 { ushort x, y, z, w; };

// f32 ws offsets (in floats)
#define ZA_OFF 0UL          // zA[512][8]
#define NW_OFF 4096UL       // nodeWe[64][256]
#define AW_OFF 20480UL      // adjWe[512]
#define BW_OFF 20992UL      // bondWe[4][512]
// ushort ws offsets (in ushorts)
#define XBF_U   46080UL     // x bf16 [512][64][256]
#define ZBF_U   8434688UL   // z bf16 [512][128]
#define GWBF_U  8500224UL   // gatW bf16 [3][256][384]
#define WZBF_U  8795136UL   // z2n_w bf16 [16384][128]

__device__ inline ushort f2bf(float f) {
    uint u = __float_as_uint(f);
    uint r = (u + 0x7FFFu + ((u >> 16) & 1u)) >> 16;
    return (ushort)r;
}
__device__ inline float bf2f(ushort u) { return __uint_as_float(((uint)u) << 16); }

// ---------------------------------------------------------------- setup ----
__global__ __launch_bounds__(256) void k_setup(
    const float* __restrict__ z, const float* __restrict__ z2nA,
    const float* __restrict__ nodeW, const float* __restrict__ nodeA, const float* __restrict__ nodeB,
    const float* __restrict__ adjW, const float* __restrict__ adjA, const float* __restrict__ adjB,
    const float* __restrict__ bondW, const float* __restrict__ bondA, const float* __restrict__ bondB,
    const float* __restrict__ gatW, const float* __restrict__ z2nw,
    float* __restrict__ wsf)
{
    ushort* wsu = (ushort*)wsf;
    int gid = blockIdx.x * 256 + threadIdx.x;
    if (gid < 4096) {                       // zA[b][r] = z[b]·A[r]
        int b = gid >> 3, r = gid & 7;
        const float* zp = z + (size_t)b * 128;
        const float* ap = z2nA + (size_t)r * 128;
        float s = 0.f;
        #pragma unroll 8
        for (int k = 0; k < 128; ++k) s += zp[k] * ap[k];
        wsf[ZA_OFF + gid] = s;
    } else if (gid < 20480) {               // nodeWe[f][c]
        int i = gid - 4096;
        int f = i >> 8, c = i & 255;
        float s = 0.f;
        #pragma unroll
        for (int r = 0; r < 8; ++r) s += nodeB[f*8+r] * nodeA[r*256+c];
        wsf[NW_OFF + i] = nodeW[i] + 2.0f * s;
    } else if (gid < 20992) {               // adjWe[c2]
        int c2 = gid - 20480;
        float s = 0.f;
        #pragma unroll
        for (int r = 0; r < 8; ++r) s += adjB[r] * adjA[r*512+c2];
        wsf[AW_OFF + c2] = adjW[c2] + 2.0f * s;
    } else if (gid < 23040) {               // bondWe[q][c2]
        int i = gid - 20992;
        int q = i >> 9, c2 = i & 511;
        float s = 0.f;
        #pragma unroll
        for (int r = 0; r < 8; ++r) s += bondB[q*8+r] * bondA[r*512+c2];
        wsf[BW_OFF + i] = bondW[i] + 2.0f * s;
    } else {                                // f32 -> bf16 conversions, 4/thread
        int cid = gid - 23040;
        const float* src; ushort* dst; int idx;
        if (cid < 16384)        { src = z;     dst = wsu + ZBF_U;  idx = cid; }
        else if (cid < 90112)   { src = gatW;  dst = wsu + GWBF_U; idx = cid - 16384; }
        else if (cid < 614400)  { src = z2nw;  dst = wsu + WZBF_U; idx = cid - 90112; }
        else return;
        float4 v = ((const float4*)src)[idx];
        us4 o; o.x = f2bf(v.x); o.y = f2bf(v.y); o.z = f2bf(v.z); o.w = f2bf(v.w);
        ((us4*)dst)[idx] = o;
    }
}

// ------------------------------------------------------------- z_to_nodes --
// computes x[brow][o] = relu(z[brow]·W[o] + 2*zA[brow]·B2[o] + bias[o]) via
// operand-swapped MFMA: A = W rows (o), B = z rows (brow); C'[o][brow].
__global__ __launch_bounds__(256) void k_z2n(
    const float* __restrict__ bias, const float* __restrict__ lB,
    float* __restrict__ wsf)
{
    ushort* wsu = (ushort*)wsf;
    int t = threadIdx.x;
    int w = t >> 6, ln = t & 63, lo = ln & 15, hi = ln >> 4;
    int bm = blockIdx.x >> 6, bn = blockIdx.x & 63;
    int brow0 = bm * 64;
    int o0 = bn * 256 + w * 64;
    const ushort* wz = wsu + WZBF_U;
    const ushort* zb = wsu + ZBF_U;
    float4v acc[4][4];
    #pragma unroll
    for (int m = 0; m < 4; ++m)
        #pragma unroll
        for (int n = 0; n < 4; ++n) acc[m][n] = (float4v)(0.f);
    #pragma unroll
    for (int kk = 0; kk < 4; ++kk) {
        short8v a[4], bq[4];
        #pragma unroll
        for (int m = 0; m < 4; ++m)
            a[m] = *(const short8v*)(wz + (size_t)(o0 + m*16 + lo)*128 + kk*32 + hi*8);
        #pragma unroll
        for (int n = 0; n < 4; ++n)
            bq[n] = *(const short8v*)(zb + (size_t)(brow0 + n*16 + lo)*128 + kk*32 + hi*8);
        #pragma unroll
        for (int m = 0; m < 4; ++m)
            #pragma unroll
            for (int n = 0; n < 4; ++n)
                acc[m][n] = __builtin_amdgcn_mfma_f32_16x16x32_bf16(a[m], bq[n], acc[m][n], 0, 0, 0);
    }
    const float* zA = wsf + ZA_OFF;
    float4 za0[4], za1[4];
    #pragma unroll
    for (int n = 0; n < 4; ++n) {
        int brow = brow0 + n*16 + lo;
        za0[n] = *(const float4*)&zA[brow*8];
        za1[n] = *(const float4*)&zA[brow*8 + 4];
    }
    #pragma unroll
    for (int m = 0; m < 4; ++m) {
        float lor[4][4]; float bs[4];
        #pragma unroll
        for (int q = 0; q < 4; ++q) {
            int o = o0 + m*16 + hi*4 + q;
            float4 b20 = *(const float4*)&lB[(size_t)o*8];
            float4 b21 = *(const float4*)&lB[(size_t)o*8 + 4];
            bs[q] = bias[o];
            #pragma unroll
            for (int n = 0; n < 4; ++n)
                lor[n][q] = za0[n].x*b20.x + za0[n].y*b20.y + za0[n].z*b20.z + za0[n].w*b20.w
                          + za1[n].x*b21.x + za1[n].y*b21.y + za1[n].z*b21.z + za1[n].w*b21.w;
        }
        #pragma unroll
        for (int n = 0; n < 4; ++n) {
            int brow = brow0 + n*16 + lo;
            float v0 = acc[m][n][0] + 2.f*lor[n][0] + bs[0]; v0 = v0 > 0.f ? v0 : 0.f;
            float v1 = acc[m][n][1] + 2.f*lor[n][1] + bs[1]; v1 = v1 > 0.f ? v1 : 0.f;
            float v2 = acc[m][n][2] + 2.f*lor[n][2] + bs[2]; v2 = v2 > 0.f ? v2 : 0.f;
            float v3 = acc[m][n][3] + 2.f*lor[n][3] + bs[3]; v3 = v3 > 0.f ? v3 : 0.f;
            us4 pk; pk.x = f2bf(v0); pk.y = f2bf(v1); pk.z = f2bf(v2); pk.w = f2bf(v3);
            *(us4*)(wsu + XBF_U + (size_t)brow*16384 + o0 + m*16 + hi*4) = pk;
        }
    }
}

// ----------------------------------------------------- fused GAT layer -----
// grid=512 (one block per graph), 4 waves, wave w == head w. Independent waves.
__global__ __launch_bounds__(256) void k_gat(
    const float* __restrict__ asrc_all, const float* __restrict__ adst_all,
    const float* __restrict__ gbias, int l, float* __restrict__ wsf)
{
    __shared__ ushort hT[4][64][72];          // per wave: hT[c][j] bf16
    __shared__ float es[4][64], ed[4][64], mrow[4][64], rsv[4][64];
    ushort* wsu = (ushort*)wsf;
    int t = threadIdx.x;
    int w = t >> 6, ln = t & 63, lo = ln & 15, hi = ln >> 4;
    int b = blockIdx.x;
    const ushort* xb  = wsu + XBF_U + (size_t)b * 16384;
    const ushort* zbp = wsu + ZBF_U + (size_t)b * 128;
    const ushort* wl  = wsu + GWBF_U + (size_t)l * 98304 + (size_t)w * 24576;

    // ---- h-GEMM: h[r][c] (r node, c channel within head), K = 384
    float4v acc[4][4];
    #pragma unroll
    for (int m = 0; m < 4; ++m)
        #pragma unroll
        for (int n = 0; n < 4; ++n) acc[m][n] = (float4v)(0.f);
    #pragma unroll
    for (int kk = 0; kk < 12; ++kk) {
        short8v a[4], bq[4];
        if (kk < 8) {
            #pragma unroll
            for (int m = 0; m < 4; ++m)
                a[m] = *(const short8v*)(xb + (size_t)(m*16 + lo)*256 + kk*32 + hi*8);
        } else {
            short8v az = *(const short8v*)(zbp + (kk-8)*32 + hi*8);
            a[0] = az; a[1] = az; a[2] = az; a[3] = az;
        }
        #pragma unroll
        for (int n = 0; n < 4; ++n)
            bq[n] = *(const short8v*)(wl + (size_t)(n*16 + lo)*384 + kk*32 + hi*8);
        #pragma unroll
        for (int m = 0; m < 4; ++m)
            #pragma unroll
            for (int n = 0; n < 4; ++n)
                acc[m][n] = __builtin_amdgcn_mfma_f32_16x16x32_bf16(a[m], bq[n], acc[m][n], 0, 0, 0);
    }

    // ---- e-dots: es[r]=h[r]·asrc, ed[r]=h[r]·adst  (reduce over c)
    float asv[4], adv[4];
    #pragma unroll
    for (int n = 0; n < 4; ++n) {
        asv[n] = asrc_all[l*256 + w*64 + n*16 + lo];
        adv[n] = adst_all[l*256 + w*64 + n*16 + lo];
    }
    #pragma unroll
    for (int m = 0; m < 4; ++m) {
        float ps0=0,ps1=0,ps2=0,ps3=0, pd0=0,pd1=0,pd2=0,pd3=0;
        #pragma unroll
        for (int n = 0; n < 4; ++n) {
            ps0 += acc[m][n][0]*asv[n]; pd0 += acc[m][n][0]*adv[n];
            ps1 += acc[m][n][1]*asv[n]; pd1 += acc[m][n][1]*adv[n];
            ps2 += acc[m][n][2]*asv[n]; pd2 += acc[m][n][2]*adv[n];
            ps3 += acc[m][n][3]*asv[n]; pd3 += acc[m][n][3]*adv[n];
        }
        #pragma unroll
        for (int mask = 1; mask < 16; mask <<= 1) {
            ps0 += __shfl_xor(ps0, mask); pd0 += __shfl_xor(pd0, mask);
            ps1 += __shfl_xor(ps1, mask); pd1 += __shfl_xor(pd1, mask);
            ps2 += __shfl_xor(ps2, mask); pd2 += __shfl_xor(pd2, mask);
            ps3 += __shfl_xor(ps3, mask); pd3 += __shfl_xor(pd3, mask);
        }
        if (lo == 0) {
            *(float4*)&es[w][m*16 + hi*4] = make_float4(ps0, ps1, ps2, ps3);
            *(float4*)&ed[w][m*16 + hi*4] = make_float4(pd0, pd1, pd2, pd3);
        }
    }

    // ---- hT[c][r] bf16 (packed 4 consecutive r)
    #pragma unroll
    for (int m = 0; m < 4; ++m)
        #pragma unroll
        for (int n = 0; n < 4; ++n) {
            us4 pk;
            pk.x = f2bf(acc[m][n][0]); pk.y = f2bf(acc[m][n][1]);
            pk.z = f2bf(acc[m][n][2]); pk.w = f2bf(acc[m][n][3]);
            *(us4*)&hT[w][n*16 + lo][m*16 + hi*4] = pk;
        }

    // ---- softmax stats per target row (one row per lane)
    {
        float edr = ed[w][ln];
        float mx = -1e30f;
        for (int j = 0; j < 64; ++j) {
            float e = edr + es[w][j];
            e = fmaxf(e, 0.2f * e);
            mx = fmaxf(mx, e);
        }
        float ss = 0.f;
        for (int j = 0; j < 64; ++j) {
            float e = edr + es[w][j];
            e = fmaxf(e, 0.2f * e);
            ss += __expf(e - mx);
        }
        mrow[w][ln] = mx;
        rsv[w][ln] = 1.0f / ss;
    }

    // ---- PV (swapped): out^T[c][r] = sum_j h[j][c] * alpha[r][j]
    float4v acc2[4][4];
    #pragma unroll
    for (int m = 0; m < 4; ++m)
        #pragma unroll
        for (int n = 0; n < 4; ++n) acc2[m][n] = (float4v)(0.f);
    #pragma unroll
    for (int kk = 0; kk < 2; ++kk) {
        short8v hb[4];
        #pragma unroll
        for (int m = 0; m < 4; ++m)
            hb[m] = *(const short8v*)&hT[w][m*16 + lo][kk*32 + hi*8];
        #pragma unroll
        for (int n = 0; n < 4; ++n) {
            int r = n*16 + lo;
            float mr = mrow[w][r], edr2 = ed[w][r];
            short8v af;
            #pragma unroll
            for (int jj = 0; jj < 8; ++jj) {
                int j = kk*32 + hi*8 + jj;
                float e = edr2 + es[w][j];
                e = fmaxf(e, 0.2f * e);
                af[jj] = (short)f2bf(__expf(e - mr));
            }
            #pragma unroll
            for (int m = 0; m < 4; ++m)
                acc2[m][n] = __builtin_amdgcn_mfma_f32_16x16x32_bf16(hb[m], af, acc2[m][n], 0, 0, 0);
        }
    }

    float rsn[4];
    #pragma unroll
    for (int n = 0; n < 4; ++n) rsn[n] = rsv[w][n*16 + lo];

    __syncthreads();   // all waves done reading x[b] before overwriting it

    // ---- epilogue: scale rows by 1/sum, +bias, relu, bf16, packed stores
    #pragma unroll
    for (int m = 0; m < 4; ++m) {
        int c0 = w*64 + m*16 + hi*4;
        float b0 = gbias[l*256 + c0 + 0];
        float b1 = gbias[l*256 + c0 + 1];
        float b2 = gbias[l*256 + c0 + 2];
        float b3 = gbias[l*256 + c0 + 3];
        #pragma unroll
        for (int n = 0; n < 4; ++n) {
            int r = n*16 + lo;
            float v0 = acc2[m][n][0]*rsn[n] + b0; v0 = v0 > 0.f ? v0 : 0.f;
            float v1 = acc2[m][n][1]*rsn[n] + b1; v1 = v1 > 0.f ? v1 : 0.f;
            float v2 = acc2[m][n][2]*rsn[n] + b2; v2 = v2 > 0.f ? v2 : 0.f;
            float v3 = acc2[m][n][3]*rsn[n] + b3; v3 = v3 > 0.f ? v3 : 0.f;
            us4 pk; pk.x = f2bf(v0); pk.y = f2bf(v1); pk.z = f2bf(v2); pk.w = f2bf(v3);
            *(us4*)(wsu + XBF_U + (size_t)b*16384 + (size_t)r*256 + c0) = pk;
        }
    }
}

// ------------------------------------------------------------- predictors --
__global__ __launch_bounds__(256) void k_pred(
    const float* __restrict__ nodeb, const float* __restrict__ adjb,
    const float* __restrict__ bondb, const float* __restrict__ wsf,
    float* __restrict__ out)
{
    __shared__ float xl[64][68];
    __shared__ float wn[64][68];
    __shared__ float s1l[64], s2l[64];
    __shared__ float t1l[64][4], t2l[64][4];
    const ushort* wsu = (const ushort*)wsf;
    int t = threadIdx.x;
    int b = blockIdx.x;
    int tr = t >> 4, tc = t & 15;
    int role = t >> 6, n2 = t & 63;
    const ushort* xb    = wsu + XBF_U + (size_t)b * 16384;
    const float* nodeWe = wsf + NW_OFF;
    const float* adjWe  = wsf + AW_OFF;
    const float* bondWe = wsf + BW_OFF;
    float acc[4][4] = {};
    float p0 = 0.f, p1 = 0.f, p2 = 0.f, p3 = 0.f;
    for (int kc = 0; kc < 4; ++kc) {
        int k0 = kc * 64;
        __syncthreads();
        for (int idx = t; idx < 1024; idx += 256) {
            int row = idx >> 4, k4 = (idx & 15) * 4;
            us4 raw = *(const us4*)&xb[(size_t)row*256 + k0 + k4];
            xl[row][k4+0] = bf2f(raw.x); xl[row][k4+1] = bf2f(raw.y);
            xl[row][k4+2] = bf2f(raw.z); xl[row][k4+3] = bf2f(raw.w);
            *(float4*)&wn[row][k4] = *(const float4*)&nodeWe[(size_t)row*256 + k0 + k4];
        }
        __syncthreads();
        #pragma unroll
        for (int k = 0; k < 64; k += 4) {
            float4 av[4], bv[4];
            #pragma unroll
            for (int i = 0; i < 4; ++i) av[i] = *(const float4*)&xl[tr+16*i][k];
            #pragma unroll
            for (int j = 0; j < 4; ++j) bv[j] = *(const float4*)&wn[tc+16*j][k];
            #pragma unroll
            for (int i = 0; i < 4; ++i)
                #pragma unroll
                for (int j = 0; j < 4; ++j)
                    acc[i][j] += av[i].x*bv[j].x + av[i].y*bv[j].y + av[i].z*bv[j].z + av[i].w*bv[j].w;
        }
        if (role == 0) {
            for (int c = 0; c < 64; ++c) p0 += xl[n2][c] * adjWe[k0+c];
        } else if (role == 1) {
            for (int c = 0; c < 64; ++c) p0 += xl[n2][c] * adjWe[256+k0+c];
        } else if (role == 2) {
            for (int c = 0; c < 64; ++c) {
                float xv = xl[n2][c];
                p0 += xv*bondWe[k0+c];      p1 += xv*bondWe[512+k0+c];
                p2 += xv*bondWe[1024+k0+c]; p3 += xv*bondWe[1536+k0+c];
            }
        } else {
            for (int c = 0; c < 64; ++c) {
                float xv = xl[n2][c];
                p0 += xv*bondWe[256+k0+c];  p1 += xv*bondWe[768+k0+c];
                p2 += xv*bondWe[1280+k0+c]; p3 += xv*bondWe[1792+k0+c];
            }
        }
    }
    __syncthreads();
    if (role == 0)      s1l[n2] = p0;
    else if (role == 1) s2l[n2] = p0;
    else if (role == 2) { t1l[n2][0]=p0; t1l[n2][1]=p1; t1l[n2][2]=p2; t1l[n2][3]=p3; }
    else                { t2l[n2][0]=p0; t2l[n2][1]=p1; t2l[n2][2]=p2; t2l[n2][3]=p3; }
    __syncthreads();
    #pragma unroll
    for (int i = 0; i < 4; ++i) {
        int n = tr + 16*i;
        #pragma unroll
        for (int j = 0; j < 4; ++j) {
            int f = tc + 16*j;
            out[(size_t)b*4096 + (size_t)n*64 + f] = acc[i][j] + nodeb[f];
        }
    }
    float ab = adjb[0];
    {
        int i = t >> 2, jg = (t & 3) * 16;
        #pragma unroll
        for (int u4 = 0; u4 < 4; ++u4) {
            float4 v;
            float* vp = (float*)&v;
            #pragma unroll
            for (int uu = 0; uu < 4; ++uu) {
                int j = jg + u4*4 + uu;
                float val;
                if (i == j)      val = 0.f;
                else if (i < j)  val = s1l[i] + s2l[j] + ab;
                else             val = s1l[j] + s2l[i] + ab;
                vp[uu] = val;
            }
            *(float4*)&out[2097152UL + (size_t)b*4096 + (size_t)i*64 + jg + u4*4] = v;
        }
    }
    float4 bb4 = *(const float4*)bondb;
    {
        int i = t >> 2, jg = (t & 3) * 16;
        #pragma unroll
        for (int u = 0; u < 16; ++u) {
            int j = jg + u;
            float4 v;
            if (i == j) { v.x = v.y = v.z = v.w = 0.f; }
            else {
                int a = i < j ? i : j, c = i < j ? j : i;
                v.x = t1l[a][0] + t2l[c][0] + bb4.x;
                v.y = t1l[a][1] + t2l[c][1] + bb4.y;
                v.z = t1l[a][2] + t2l[c][2] + bb4.z;
                v.w = t1l[a][3] + t2l[c][3] + bb4.w;
            }
            *(float4*)&out[4194304UL + (size_t)b*16384 + (size_t)(i*64+j)*4] = v;
        }
    }
}

// ------------------------------------------------------------------ host ---
extern "C" void kernel_launch(void* const* d_in, const int* in_sizes, int n_in,
                              void* d_out, int out_size, void* d_ws, size_t ws_size,
                              hipStream_t stream)
{
    const float* z     = (const float*)d_in[0];
    const float* z2nw  = (const float*)d_in[1];
    const float* z2nb  = (const float*)d_in[2];
    const float* z2nA  = (const float*)d_in[3];
    const float* z2nB  = (const float*)d_in[4];
    const float* gatW  = (const float*)d_in[5];
    const float* asrc  = (const float*)d_in[6];
    const float* adst  = (const float*)d_in[7];
    const float* gbias = (const float*)d_in[8];
    const float* nodew = (const float*)d_in[9];
    const float* nodeb = (const float*)d_in[10];
    const float* nodeA = (const float*)d_in[11];
    const float* nodeB = (const float*)d_in[12];
    const float* adjw  = (const float*)d_in[13];
    const float* adjb  = (const float*)d_in[14];
    const float* adjA  = (const float*)d_in[15];
    const float* adjB  = (const float*)d_in[16];
    const float* bondw = (const float*)d_in[17];
    const float* bondb = (const float*)d_in[18];
    const float* bondA = (const float*)d_in[19];
    const float* bondB = (const float*)d_in[20];
    float* ws  = (float*)d_ws;
    float* out = (float*)d_out;

    k_setup<<<2490, 256, 0, stream>>>(z, z2nA, nodew, nodeA, nodeB,
                                      adjw, adjA, adjB, bondw, bondA, bondB,
                                      gatW, z2nw, ws);
    k_z2n<<<512, 256, 0, stream>>>(z2nb, z2nB, ws);
    for (int l = 0; l < 3; ++l)
        k_gat<<<512, 256, 0, stream>>>(asrc, adst, gbias, l, ws);
    k_pred<<<512, 256, 0, stream>>>(nodeb, adjb, bondb, ws, out);
}

// Round 3
// 147.510 us; speedup vs baseline: 6.2667x; 1.5257x over previous
//
#include <hip/hip_runtime.h>

// B=512, N=64, H=256, LAT=128, HEADS=4, HC=64, NF=64, L=3, R=8, SCAL=2.0, NB=4, Din=384

typedef float float4v __attribute__((ext_vector_type(4)));
typedef short short8v __attribute__((ext_vector_type(8)));

struct alignas(8) us4 { ushort x, y, z, w; };

// f32 ws offsets (in floats)
#define ZA_OFF 0UL          // zA[512][8]
// ushort ws offsets (in ushorts)
#define XBF_U   46080UL     // x bf16 [512][64][256]
#define ZBF_U   8434688UL   // z bf16 [512][128]
#define GWBF_U  8500224UL   // gatW bf16 [3][256][384]
#define WZBF_U  8795136UL   // z2n_w bf16 [16384][128]
#define PW_U    10892288UL  // pred weights bf16 [80][256]

__device__ inline ushort f2bf(float f) {
    uint u = __float_as_uint(f);
    uint r = (u + 0x7FFFu + ((u >> 16) & 1u)) >> 16;
    return (ushort)r;
}
__device__ inline float bf2f(ushort u) { return __uint_as_float(((uint)u) << 16); }

// ---------------------------------------------------------------- setup ----
__global__ __launch_bounds__(256) void k_setup(
    const float* __restrict__ z, const float* __restrict__ z2nA,
    const float* __restrict__ nodeW, const float* __restrict__ nodeA, const float* __restrict__ nodeB,
    const float* __restrict__ adjW, const float* __restrict__ adjA, const float* __restrict__ adjB,
    const float* __restrict__ bondW, const float* __restrict__ bondA, const float* __restrict__ bondB,
    const float* __restrict__ gatW, const float* __restrict__ z2nw,
    float* __restrict__ wsf)
{
    ushort* wsu = (ushort*)wsf;
    int gid = blockIdx.x * 256 + threadIdx.x;
    if (gid < 4096) {                       // zA[b][r] = z[b]·A[r]
        int b = gid >> 3, r = gid & 7;
        const float* zp = z + (size_t)b * 128;
        const float* ap = z2nA + (size_t)r * 128;
        float s = 0.f;
        #pragma unroll 8
        for (int k = 0; k < 128; ++k) s += zp[k] * ap[k];
        wsf[ZA_OFF + gid] = s;
    } else if (gid < 24576) {               // pw[80][256] bf16, LoRA folded
        int idx = gid - 4096;
        int r = idx >> 8, c = idx & 255;
        float v = 0.f;
        if (r < 64) {
            float s = 0.f;
            #pragma unroll
            for (int k = 0; k < 8; ++k) s += nodeB[r*8+k] * nodeA[k*256+c];
            v = nodeW[r*256+c] + 2.0f * s;
        } else if (r < 66) {
            int off = (r - 64) * 256 + c;
            float s = 0.f;
            #pragma unroll
            for (int k = 0; k < 8; ++k) s += adjB[k] * adjA[k*512+off];
            v = adjW[off] + 2.0f * s;
        } else if (r < 70) {
            int q = r - 66;
            float s = 0.f;
            #pragma unroll
            for (int k = 0; k < 8; ++k) s += bondB[q*8+k] * bondA[k*512+c];
            v = bondW[q*512+c] + 2.0f * s;
        } else if (r < 74) {
            int q = r - 70;
            float s = 0.f;
            #pragma unroll
            for (int k = 0; k < 8; ++k) s += bondB[q*8+k] * bondA[k*512+256+c];
            v = bondW[q*512+256+c] + 2.0f * s;
        }
        wsu[PW_U + idx] = f2bf(v);
    } else {                                // f32 -> bf16 conversions, 4/thread
        int cid = gid - 24576;
        const float* src; ushort* dst; int idx;
        if (cid < 16384)        { src = z;     dst = wsu + ZBF_U;  idx = cid; }
        else if (cid < 90112)   { src = gatW;  dst = wsu + GWBF_U; idx = cid - 16384; }
        else if (cid < 614400)  { src = z2nw;  dst = wsu + WZBF_U; idx = cid - 90112; }
        else return;
        float4 v = ((const float4*)src)[idx];
        us4 o; o.x = f2bf(v.x); o.y = f2bf(v.y); o.z = f2bf(v.z); o.w = f2bf(v.w);
        ((us4*)dst)[idx] = o;
    }
}

// ------------------------------------------------------------- z_to_nodes --
__global__ __launch_bounds__(256) void k_z2n(
    const float* __restrict__ bias, const float* __restrict__ lB,
    float* __restrict__ wsf)
{
    ushort* wsu = (ushort*)wsf;
    int t = threadIdx.x;
    int w = t >> 6, ln = t & 63, lo = ln & 15, hi = ln >> 4;
    int bm = blockIdx.x >> 6, bn = blockIdx.x & 63;
    int brow0 = bm * 64;
    int o0 = bn * 256 + w * 64;
    const ushort* wz = wsu + WZBF_U;
    const ushort* zb = wsu + ZBF_U;
    float4v acc[4][4];
    #pragma unroll
    for (int m = 0; m < 4; ++m)
        #pragma unroll
        for (int n = 0; n < 4; ++n) acc[m][n] = (float4v)(0.f);
    #pragma unroll
    for (int kk = 0; kk < 4; ++kk) {
        short8v a[4], bq[4];
        #pragma unroll
        for (int m = 0; m < 4; ++m)
            a[m] = *(const short8v*)(wz + (size_t)(o0 + m*16 + lo)*128 + kk*32 + hi*8);
        #pragma unroll
        for (int n = 0; n < 4; ++n)
            bq[n] = *(const short8v*)(zb + (size_t)(brow0 + n*16 + lo)*128 + kk*32 + hi*8);
        #pragma unroll
        for (int m = 0; m < 4; ++m)
            #pragma unroll
            for (int n = 0; n < 4; ++n)
                acc[m][n] = __builtin_amdgcn_mfma_f32_16x16x32_bf16(a[m], bq[n], acc[m][n], 0, 0, 0);
    }
    const float* zA = wsf + ZA_OFF;
    float4 za0[4], za1[4];
    #pragma unroll
    for (int n = 0; n < 4; ++n) {
        int brow = brow0 + n*16 + lo;
        za0[n] = *(const float4*)&zA[brow*8];
        za1[n] = *(const float4*)&zA[brow*8 + 4];
    }
    #pragma unroll
    for (int m = 0; m < 4; ++m) {
        float lor[4][4]; float bs[4];
        #pragma unroll
        for (int q = 0; q < 4; ++q) {
            int o = o0 + m*16 + hi*4 + q;
            float4 b20 = *(const float4*)&lB[(size_t)o*8];
            float4 b21 = *(const float4*)&lB[(size_t)o*8 + 4];
            bs[q] = bias[o];
            #pragma unroll
            for (int n = 0; n < 4; ++n)
                lor[n][q] = za0[n].x*b20.x + za0[n].y*b20.y + za0[n].z*b20.z + za0[n].w*b20.w
                          + za1[n].x*b21.x + za1[n].y*b21.y + za1[n].z*b21.z + za1[n].w*b21.w;
        }
        #pragma unroll
        for (int n = 0; n < 4; ++n) {
            int brow = brow0 + n*16 + lo;
            float v0 = acc[m][n][0] + 2.f*lor[n][0] + bs[0]; v0 = v0 > 0.f ? v0 : 0.f;
            float v1 = acc[m][n][1] + 2.f*lor[n][1] + bs[1]; v1 = v1 > 0.f ? v1 : 0.f;
            float v2 = acc[m][n][2] + 2.f*lor[n][2] + bs[2]; v2 = v2 > 0.f ? v2 : 0.f;
            float v3 = acc[m][n][3] + 2.f*lor[n][3] + bs[3]; v3 = v3 > 0.f ? v3 : 0.f;
            us4 pk; pk.x = f2bf(v0); pk.y = f2bf(v1); pk.z = f2bf(v2); pk.w = f2bf(v3);
            *(us4*)(wsu + XBF_U + (size_t)brow*16384 + o0 + m*16 + hi*4) = pk;
        }
    }
}

// ----------------------------------------------------- fused GAT layer -----
__global__ __launch_bounds__(256) void k_gat(
    const float* __restrict__ asrc_all, const float* __restrict__ adst_all,
    const float* __restrict__ gbias, int l, float* __restrict__ wsf)
{
    __shared__ ushort hT[4][64][72];          // per wave: hT[c][j] bf16
    __shared__ float es[4][64], ed[4][64], mrow[4][64], rsv[4][64];
    ushort* wsu = (ushort*)wsf;
    int t = threadIdx.x;
    int w = t >> 6, ln = t & 63, lo = ln & 15, hi = ln >> 4;
    int b = blockIdx.x;
    const ushort* xb  = wsu + XBF_U + (size_t)b * 16384;
    const ushort* zbp = wsu + ZBF_U + (size_t)b * 128;
    const ushort* wl  = wsu + GWBF_U + (size_t)l * 98304 + (size_t)w * 24576;

    float4v acc[4][4];
    #pragma unroll
    for (int m = 0; m < 4; ++m)
        #pragma unroll
        for (int n = 0; n < 4; ++n) acc[m][n] = (float4v)(0.f);
    #pragma unroll
    for (int kk = 0; kk < 12; ++kk) {
        short8v a[4], bq[4];
        if (kk < 8) {
            #pragma unroll
            for (int m = 0; m < 4; ++m)
                a[m] = *(const short8v*)(xb + (size_t)(m*16 + lo)*256 + kk*32 + hi*8);
        } else {
            short8v az = *(const short8v*)(zbp + (kk-8)*32 + hi*8);
            a[0] = az; a[1] = az; a[2] = az; a[3] = az;
        }
        #pragma unroll
        for (int n = 0; n < 4; ++n)
            bq[n] = *(const short8v*)(wl + (size_t)(n*16 + lo)*384 + kk*32 + hi*8);
        #pragma unroll
        for (int m = 0; m < 4; ++m)
            #pragma unroll
            for (int n = 0; n < 4; ++n)
                acc[m][n] = __builtin_amdgcn_mfma_f32_16x16x32_bf16(a[m], bq[n], acc[m][n], 0, 0, 0);
    }

    float asv[4], adv[4];
    #pragma unroll
    for (int n = 0; n < 4; ++n) {
        asv[n] = asrc_all[l*256 + w*64 + n*16 + lo];
        adv[n] = adst_all[l*256 + w*64 + n*16 + lo];
    }
    #pragma unroll
    for (int m = 0; m < 4; ++m) {
        float ps0=0,ps1=0,ps2=0,ps3=0, pd0=0,pd1=0,pd2=0,pd3=0;
        #pragma unroll
        for (int n = 0; n < 4; ++n) {
            ps0 += acc[m][n][0]*asv[n]; pd0 += acc[m][n][0]*adv[n];
            ps1 += acc[m][n][1]*asv[n]; pd1 += acc[m][n][1]*adv[n];
            ps2 += acc[m][n][2]*asv[n]; pd2 += acc[m][n][2]*adv[n];
            ps3 += acc[m][n][3]*asv[n]; pd3 += acc[m][n][3]*adv[n];
        }
        #pragma unroll
        for (int mask = 1; mask < 16; mask <<= 1) {
            ps0 += __shfl_xor(ps0, mask); pd0 += __shfl_xor(pd0, mask);
            ps1 += __shfl_xor(ps1, mask); pd1 += __shfl_xor(pd1, mask);
            ps2 += __shfl_xor(ps2, mask); pd2 += __shfl_xor(pd2, mask);
            ps3 += __shfl_xor(ps3, mask); pd3 += __shfl_xor(pd3, mask);
        }
        if (lo == 0) {
            *(float4*)&es[w][m*16 + hi*4] = make_float4(ps0, ps1, ps2, ps3);
            *(float4*)&ed[w][m*16 + hi*4] = make_float4(pd0, pd1, pd2, pd3);
        }
    }

    #pragma unroll
    for (int m = 0; m < 4; ++m)
        #pragma unroll
        for (int n = 0; n < 4; ++n) {
            us4 pk;
            pk.x = f2bf(acc[m][n][0]); pk.y = f2bf(acc[m][n][1]);
            pk.z = f2bf(acc[m][n][2]); pk.w = f2bf(acc[m][n][3]);
            *(us4*)&hT[w][n*16 + lo][m*16 + hi*4] = pk;
        }

    {
        float edr = ed[w][ln];
        float mx = -1e30f;
        for (int j = 0; j < 64; ++j) {
            float e = edr + es[w][j];
            e = fmaxf(e, 0.2f * e);
            mx = fmaxf(mx, e);
        }
        float ss = 0.f;
        for (int j = 0; j < 64; ++j) {
            float e = edr + es[w][j];
            e = fmaxf(e, 0.2f * e);
            ss += __expf(e - mx);
        }
        mrow[w][ln] = mx;
        rsv[w][ln] = 1.0f / ss;
    }

    float4v acc2[4][4];
    #pragma unroll
    for (int m = 0; m < 4; ++m)
        #pragma unroll
        for (int n = 0; n < 4; ++n) acc2[m][n] = (float4v)(0.f);
    #pragma unroll
    for (int kk = 0; kk < 2; ++kk) {
        short8v hb[4];
        #pragma unroll
        for (int m = 0; m < 4; ++m)
            hb[m] = *(const short8v*)&hT[w][m*16 + lo][kk*32 + hi*8];
        #pragma unroll
        for (int n = 0; n < 4; ++n) {
            int r = n*16 + lo;
            float mr = mrow[w][r], edr2 = ed[w][r];
            short8v af;
            #pragma unroll
            for (int jj = 0; jj < 8; ++jj) {
                int j = kk*32 + hi*8 + jj;
                float e = edr2 + es[w][j];
                e = fmaxf(e, 0.2f * e);
                af[jj] = (short)f2bf(__expf(e - mr));
            }
            #pragma unroll
            for (int m = 0; m < 4; ++m)
                acc2[m][n] = __builtin_amdgcn_mfma_f32_16x16x32_bf16(hb[m], af, acc2[m][n], 0, 0, 0);
        }
    }

    float rsn[4];
    #pragma unroll
    for (int n = 0; n < 4; ++n) rsn[n] = rsv[w][n*16 + lo];

    __syncthreads();

    #pragma unroll
    for (int m = 0; m < 4; ++m) {
        int c0 = w*64 + m*16 + hi*4;
        float b0 = gbias[l*256 + c0 + 0];
        float b1 = gbias[l*256 + c0 + 1];
        float b2 = gbias[l*256 + c0 + 2];
        float b3 = gbias[l*256 + c0 + 3];
        #pragma unroll
        for (int n = 0; n < 4; ++n) {
            int r = n*16 + lo;
            float v0 = acc2[m][n][0]*rsn[n] + b0; v0 = v0 > 0.f ? v0 : 0.f;
            float v1 = acc2[m][n][1]*rsn[n] + b1; v1 = v1 > 0.f ? v1 : 0.f;
            float v2 = acc2[m][n][2]*rsn[n] + b2; v2 = v2 > 0.f ? v2 : 0.f;
            float v3 = acc2[m][n][3]*rsn[n] + b3; v3 = v3 > 0.f ? v3 : 0.f;
            us4 pk; pk.x = f2bf(v0); pk.y = f2bf(v1); pk.z = f2bf(v2); pk.w = f2bf(v3);
            *(us4*)(wsu + XBF_U + (size_t)b*16384 + (size_t)r*256 + c0) = pk;
        }
    }
}

// ------------------------------------------------------------- predictors --
// 1 block per graph, 4 waves. MFMA node GEMM + aux columns, coalesced writes.
__global__ __launch_bounds__(256) void k_pred(
    const float* __restrict__ nodeb, const float* __restrict__ adjb,
    const float* __restrict__ bondb, const float* __restrict__ wsf,
    float* __restrict__ out)
{
    __shared__ float s1l[64], s2l[64];
    __shared__ float t1l[64][5], t2l[64][5];
    const ushort* wsu = (const ushort*)wsf;
    int t = threadIdx.x;
    int w = t >> 6, ln = t & 63, lo = ln & 15, hi = ln >> 4;
    int b = blockIdx.x;
    const ushort* xb = wsu + XBF_U + (size_t)b * 16384;
    const ushort* pw = wsu + PW_U;

    float4v acc[5];
    #pragma unroll
    for (int n = 0; n < 5; ++n) acc[n] = (float4v)(0.f);
    #pragma unroll
    for (int kk = 0; kk < 8; ++kk) {
        short8v a = *(const short8v*)(xb + (size_t)(w*16 + lo)*256 + kk*32 + hi*8);
        #pragma unroll
        for (int n = 0; n < 5; ++n) {
            short8v bq = *(const short8v*)(pw + (size_t)(n*16 + lo)*256 + kk*32 + hi*8);
            acc[n] = __builtin_amdgcn_mfma_f32_16x16x32_bf16(a, bq, acc[n], 0, 0, 0);
        }
    }

    // node recon: D row = node (w*16+hi*4+q), D col = feature (n*16+lo)
    #pragma unroll
    for (int n = 0; n < 4; ++n) {
        float bs = nodeb[n*16 + lo];
        #pragma unroll
        for (int q = 0; q < 4; ++q) {
            int nd = w*16 + hi*4 + q;
            out[(size_t)b*4096 + (size_t)nd*64 + n*16 + lo] = acc[n][q] + bs;
        }
    }
    // aux columns -> LDS
    #pragma unroll
    for (int q = 0; q < 4; ++q) {
        int nd = w*16 + hi*4 + q;
        float v = acc[4][q];
        if (lo == 0)      s1l[nd] = v;
        else if (lo == 1) s2l[nd] = v;
        else if (lo < 6)  t1l[nd][lo-2] = v;
        else if (lo < 10) t2l[nd][lo-6] = v;
    }
    __syncthreads();

    // adj logits: contiguous float4 sweep
    float ab = adjb[0];
    #pragma unroll
    for (int it = 0; it < 4; ++it) {
        int flat = (it*256 + t) * 4;         // float index in [0,4096)
        int i = flat >> 6;
        int j0 = flat & 63;
        float4 v; float* vp = (float*)&v;
        #pragma unroll
        for (int uu = 0; uu < 4; ++uu) {
            int j = j0 + uu;
            float val;
            if (i == j)      val = 0.f;
            else if (i < j)  val = s1l[i] + s2l[j] + ab;
            else             val = s1l[j] + s2l[i] + ab;
            vp[uu] = val;
        }
        *(float4*)&out[2097152UL + (size_t)b*4096 + flat] = v;
    }

    // bond logits: contiguous float4 sweep (one float4 == one (i,j) pair)
    float4 bb = *(const float4*)bondb;
    #pragma unroll
    for (int it = 0; it < 16; ++it) {
        int fl4 = it*256 + t;                // (i*64+j) in [0,4096)
        int i = fl4 >> 6;
        int j = fl4 & 63;
        float4 v;
        if (i == j) { v.x = v.y = v.z = v.w = 0.f; }
        else {
            int a = i < j ? i : j, c = i < j ? j : i;
            v.x = t1l[a][0] + t2l[c][0] + bb.x;
            v.y = t1l[a][1] + t2l[c][1] + bb.y;
            v.z = t1l[a][2] + t2l[c][2] + bb.z;
            v.w = t1l[a][3] + t2l[c][3] + bb.w;
        }
        *(float4*)&out[4194304UL + (size_t)b*16384 + (size_t)fl4*4] = v;
    }
}

// ------------------------------------------------------------------ host ---
extern "C" void kernel_launch(void* const* d_in, const int* in_sizes, int n_in,
                              void* d_out, int out_size, void* d_ws, size_t ws_size,
                              hipStream_t stream)
{
    const float* z     = (const float*)d_in[0];
    const float* z2nw  = (const float*)d_in[1];
    const float* z2nb  = (const float*)d_in[2];
    const float* z2nA  = (const float*)d_in[3];
    const float* z2nB  = (const float*)d_in[4];
    const float* gatW  = (const float*)d_in[5];
    const float* asrc  = (const float*)d_in[6];
    const float* adst  = (const float*)d_in[7];
    const float* gbias = (const float*)d_in[8];
    const float* nodew = (const float*)d_in[9];
    const float* nodeb = (const float*)d_in[10];
    const float* nodeA = (const float*)d_in[11];
    const float* nodeB = (const float*)d_in[12];
    const float* adjw  = (const float*)d_in[13];
    const float* adjb  = (const float*)d_in[14];
    const float* adjA  = (const float*)d_in[15];
    const float* adjB  = (const float*)d_in[16];
    const float* bondw = (const float*)d_in[17];
    const float* bondb = (const float*)d_in[18];
    const float* bondA = (const float*)d_in[19];
    const float* bondB = (const float*)d_in[20];
    float* ws  = (float*)d_ws;
    float* out = (float*)d_out;

    k_setup<<<2496, 256, 0, stream>>>(z, z2nA, nodew, nodeA, nodeB,
                                      adjw, adjA, adjB, bondw, bondA, bondB,
                                      gatW, z2nw, ws);
    k_z2n<<<512, 256, 0, stream>>>(z2nb, z2nB, ws);
    for (int l = 0; l < 3; ++l)
        k_gat<<<512, 256, 0, stream>>>(asrc, adst, gbias, l, ws);
    k_pred<<<512, 256, 0, stream>>>(nodeb, adjb, bondb, ws, out);
}